// Round 8
// baseline (8919.960 us; speedup 1.0000x reference)
//
#include <hip/hip_runtime.h>
#include <hip/hip_bf16.h>
#include <cmath>

#define HID 512
#define TSTEPS 784
#define BATCH 256
#define NCLS 10
#define NBLK 256

typedef __bf16 bf16x8 __attribute__((ext_vector_type(8)));
typedef float f32x4 __attribute__((ext_vector_type(4)));
typedef int   i32x4 __attribute__((ext_vector_type(4)));

#define SWS(r) (((unsigned)(r) & 7u) << 4)

// LLC-coherent ops (bypass L1+L2; proven visible cross-XCD in rounds 4/5)
#define LDX4_CC(dst, addr) \
    asm volatile("global_load_dwordx4 %0, %1, off sc0 sc1" : "=v"(dst) : "v"(addr) : "memory")
#define STX4_CC(addr, val) \
    asm volatile("global_store_dwordx4 %0, %1, off sc0 sc1" :: "v"(addr), "v"(val) : "memory")

// zero h0w + h1w (1 MB = 65536 uint4); grid 256x256 covers exactly
__global__ void init_hw(uint4* hz) {
    hz[blockIdx.x * 256 + threadIdx.x] = make_uint4(0u, 0u, 0u, 0u);
}

__device__ __forceinline__ float sigmoid_f(float v) {
    return __fdividef(1.f, 1.f + __expf(-v));
}
__device__ __forceinline__ float tanh_f(float v) {
    float e = __expf(fminf(fmaxf(2.f * v, -30.f), 30.f));
    return __fdividef(e - 1.f, e + 1.f);
}

// Persistent LSTM, barrier-free tagged-data exchange.
// 256 blocks = 8 groups(32 batch rows) x 32 col-slices(16 cols).
// h buffers: [256 rows][128 chunks] uint4, chunk = {h01, h23, tag, 0} for 4 cols.
// Producer of step t writes tag t+1 (fire-and-forget). Consumer at step t polls
// its 32x512 slice until all tags == t, then computes. No flags, no barriers.
__global__ __launch_bounds__(256)
void lstm_persist(const float* __restrict__ x,      // [256][784]
                  const float* __restrict__ W_hh,   // [2048][512] fp32
                  const float* __restrict__ w_in,   // [2048]
                  const float* __restrict__ b_ih,
                  const float* __restrict__ b_hh,
                  uint4* __restrict__ h0w,          // [256][128] tagged chunks
                  uint4* __restrict__ h1w,
                  float* __restrict__ hf)           // [256][512] fp32
{
    __shared__ __align__(16) __bf16 wlds[64 * HID];   // 64 KB W slice, swizzled
    __shared__ __align__(16) __bf16 hlds[32 * HID];   // 32 KB h slice, swizzled
    __shared__ float gl[4][32][17];                   // gate exchange

    const int tid  = threadIdx.x;
    const int lane = tid & 63;
    const int w    = tid >> 6;           // wave id = gate (i,f,g,o)
    const int bg   = blockIdx.x >> 5;    // batch group (8)
    const int cs   = blockIdx.x & 31;    // col slice (16 cols)
    const int b0   = bg * 32;
    const int j0   = cs * 16;
    const int rlo  = lane & 15;
    const int khi  = (lane >> 4) * 8;    // elements

    // ---- stage W slice (64 rows x 512) into LDS once (fp32->bf16, swizzled) ----
    {
        int r = tid >> 2;                // local row 0..63
        int q = tid & 3;
        int s = r >> 4, jj = r & 15;
        const float* src = W_hh + (size_t)(s * HID + j0 + jj) * HID + q * 128;
        char* wp = (char*)wlds;
        unsigned rowb = (unsigned)r * (HID * 2);
        unsigned sw   = SWS(r);
        #pragma unroll
        for (int cc = 0; cc < 128; cc += 8) {
            float4 va = *(const float4*)(src + cc);
            float4 vb = *(const float4*)(src + cc + 4);
            bf16x8 pk;
            pk[0]=(__bf16)va.x; pk[1]=(__bf16)va.y; pk[2]=(__bf16)va.z; pk[3]=(__bf16)va.w;
            pk[4]=(__bf16)vb.x; pk[5]=(__bf16)vb.y; pk[6]=(__bf16)vb.z; pk[7]=(__bf16)vb.w;
            *(bf16x8*)(wp + ((rowb + (unsigned)(q * 128 + cc) * 2) ^ sw)) = pk;
        }
    }

    // cell mapping (tid<128 active): row Rc=tid>>2 (0..31), cols c4..c4+3 (of 16)
    const int c4 = (tid & 3) * 4;
    float win_r[4][4], bias_r[4][4];
    #pragma unroll
    for (int g = 0; g < 4; ++g)
        #pragma unroll
        for (int ii = 0; ii < 4; ++ii) {
            int idx = g * HID + j0 + c4 + ii;
            win_r[g][ii]  = w_in[idx];
            bias_r[g][ii] = b_ih[idx] + b_hh[idx];
        }
    float creg[4] = {0.f, 0.f, 0.f, 0.f};

    // staging mapping: row rS (0..31), segment seg (0..7) of 64 cols (16 chunks)
    const int rS  = tid & 31;
    const int seg = tid >> 5;
    const unsigned rowbS = (unsigned)rS * (HID * 2);
    const unsigned swS   = SWS(rS);

    // B-fragment base: local W row rB = w*16 + rlo
    const unsigned rBb = (unsigned)(w * 16 + rlo) * (HID * 2);
    const unsigned swB = SWS(rlo);
    const char* wbp = (const char*)wlds;
    const char* hbp = (const char*)hlds;
    char* hwp = (char*)hlds;

    __syncthreads();

    for (int t = 0; t < TSTEPS; ++t) {
        const uint4* hprevw = (t & 1) ? h1w : h0w;
        uint4* hnextw       = (t & 1) ? h0w : h1w;

        // ---- stage + poll: 16 tagged chunks (64 cols) per thread ----
        {
            const uint4* gsrc = hprevw + (size_t)(b0 + rS) * 128 + seg * 16;
            i32x4 v[16];
            unsigned bad = 1;
            while (bad) {
                #pragma unroll
                for (int i = 0; i < 16; ++i) LDX4_CC(v[i], gsrc + i);
                asm volatile("s_waitcnt vmcnt(0)" ::: "memory");
                bad = 0;
                #pragma unroll
                for (int i = 0; i < 16; ++i) bad |= ((unsigned)v[i][2]) ^ (unsigned)t;
                if (bad) __builtin_amdgcn_s_sleep(2);
            }
            __builtin_amdgcn_sched_barrier(0);
            // pack bf16 data into swizzled hlds (8 x 16B per thread)
            unsigned base = rowbS + (unsigned)seg * 128u;
            #pragma unroll
            for (int p = 0; p < 8; ++p) {
                i32x4 d;
                d[0] = v[2*p][0];   d[1] = v[2*p][1];
                d[2] = v[2*p+1][0]; d[3] = v[2*p+1][1];
                *(i32x4*)(hwp + ((base + (unsigned)p * 16u) ^ swS)) = d;
            }
        }
        __syncthreads();   // hlds ready

        // ---- gates tile: 32 rows x 16 cols for gate w ----
        f32x4 acc0 = {0.f,0.f,0.f,0.f}, acc1 = {0.f,0.f,0.f,0.f};
        #pragma unroll
        for (int ks = 0; ks < 16; ++ks) {
            unsigned colb = (unsigned)(khi * 2 + ks * 64);
            bf16x8 a0 = *(const bf16x8*)(hbp + (((unsigned)rlo * 1024u + colb) ^ SWS(rlo)));
            bf16x8 a1 = *(const bf16x8*)(hbp + (((unsigned)(16 + rlo) * 1024u + colb) ^ SWS(rlo)));
            bf16x8 b  = *(const bf16x8*)(wbp + ((rBb + colb) ^ swB));
            acc0 = __builtin_amdgcn_mfma_f32_16x16x32_bf16(a0, b, acc0, 0, 0, 0);
            acc1 = __builtin_amdgcn_mfma_f32_16x16x32_bf16(a1, b, acc1, 0, 0, 0);
        }
        #pragma unroll
        for (int rr = 0; rr < 4; ++rr) {
            int rowl = (lane >> 4) * 4 + rr;   // D: col=lane&15, row=(lane>>4)*4+reg
            gl[w][rowl][rlo]      = acc0[rr];
            gl[w][16 + rowl][rlo] = acc1[rr];
        }
        __syncthreads();   // gl ready

        // ---- cell update (tid<128: 4 cols each), tagged h store, no wait ----
        if (tid < 128) {
            const int Rc = tid >> 2;
            float xv = x[(size_t)(b0 + Rc) * TSTEPS + t];
            float hn[4];
            #pragma unroll
            for (int ii = 0; ii < 4; ++ii) {
                int ccx = c4 + ii;
                float gi = gl[0][Rc][ccx] + xv * win_r[0][ii] + bias_r[0][ii];
                float gf = gl[1][Rc][ccx] + xv * win_r[1][ii] + bias_r[1][ii];
                float gg = gl[2][Rc][ccx] + xv * win_r[2][ii] + bias_r[2][ii];
                float go = gl[3][Rc][ccx] + xv * win_r[3][ii] + bias_r[3][ii];
                float cn = sigmoid_f(gf) * creg[ii] + sigmoid_f(gi) * tanh_f(gg);
                creg[ii] = cn;
                hn[ii]   = sigmoid_f(go) * tanh_f(cn);
            }
            if (t == TSTEPS - 1) {
                *(f32x4*)(hf + (size_t)(b0 + Rc) * HID + j0 + c4) =
                    (f32x4){hn[0], hn[1], hn[2], hn[3]};
            } else {
                union { __bf16 b[2]; unsigned u; } p01, p23;
                p01.b[0] = (__bf16)hn[0]; p01.b[1] = (__bf16)hn[1];
                p23.b[0] = (__bf16)hn[2]; p23.b[1] = (__bf16)hn[3];
                i32x4 out;
                out[0] = (int)p01.u; out[1] = (int)p23.u;
                out[2] = (int)(t + 1); out[3] = 0;
                uint4* dst = hnextw + (size_t)(b0 + Rc) * 128 + cs * 4 + (tid & 3);
                STX4_CC(dst, out);
            }
        }
        // no barrier: hlds/gl reuse is protected by next iteration's syncthreads
    }
}

// out[b][j] = h_T[b] . W_lin[j] + b_lin[j]
__global__ void head(const float* __restrict__ hfp, const float* __restrict__ Wl,
                     const float* __restrict__ bl_, float* __restrict__ out)
{
    __shared__ float hr[HID];
    int b = blockIdx.x;
    for (int k = threadIdx.x; k < HID; k += blockDim.x) hr[k] = hfp[b * HID + k];
    __syncthreads();
    int j = threadIdx.x;
    if (j < NCLS) {
        float acc = bl_[j];
        for (int k = 0; k < HID; ++k) acc += hr[k] * Wl[j * HID + k];
        out[b * NCLS + j] = acc;
    }
}

extern "C" void kernel_launch(void* const* d_in, const int* in_sizes, int n_in,
                              void* d_out, int out_size, void* d_ws, size_t ws_size,
                              hipStream_t stream) {
    const float* inputs = (const float*)d_in[0];
    const float* W_ih   = (const float*)d_in[1];
    const float* W_hh   = (const float*)d_in[2];
    const float* b_ih   = (const float*)d_in[3];
    const float* b_hh   = (const float*)d_in[4];
    const float* W_lin  = (const float*)d_in[5];
    const float* b_lin  = (const float*)d_in[6];

    // ws: h0w 512K | h1w 512K | hf 512K
    const size_t OFS_H1 = 512u << 10;
    const size_t OFS_HF = 1024u << 10;
    const size_t NEEDED = 1536u << 10;
    if (ws_size < NEEDED) return;

    char* ws = (char*)d_ws;
    uint4* h0w = (uint4*)ws;
    uint4* h1w = (uint4*)(ws + OFS_H1);
    float* hf  = (float*)(ws + OFS_HF);

    init_hw<<<256, 256, 0, stream>>>((uint4*)ws);   // zeroes h0w+h1w (1 MB)

    lstm_persist<<<NBLK, 256, 0, stream>>>(inputs, W_hh, W_ih, b_ih, b_hh,
                                           h0w, h1w, hf);

    head<<<BATCH, 64, 0, stream>>>(hf, W_lin, b_lin, (float*)d_out);
}

// Round 9
// 2883.572 us; speedup vs baseline: 3.0934x; 3.0934x over previous
//
#include <hip/hip_runtime.h>
#include <hip/hip_bf16.h>
#include <cmath>

#define HID 512
#define TSTEPS 784
#define BATCH 256
#define NCLS 10
#define NBLK 256
#define GRP 16      // blocks (col slices) per group
#define NGRP 16     // groups (16 batch rows each)

typedef __bf16 bf16x8 __attribute__((ext_vector_type(8)));
typedef float f32x4 __attribute__((ext_vector_type(4)));
typedef float f32x2 __attribute__((ext_vector_type(2)));
typedef int   i32x4 __attribute__((ext_vector_type(4)));

#define SWS(r) (((unsigned)(r) & 7u) << 4)

// LLC-coherent ops (bypass L1+L2; proven cross-XCD-visible rounds 4/5)
#define LDX4_CC(dst, addr) \
    asm volatile("global_load_dwordx4 %0, %1, off sc0 sc1" : "=v"(dst) : "v"(addr) : "memory")
#define STOREDW_CC(addr, val) \
    asm volatile("global_store_dword %0, %1, off sc0 sc1" :: "v"(addr), "v"(val) : "memory")

__device__ __forceinline__ i32x4 ldflags_cc(const unsigned* a) {
    i32x4 d;
    asm volatile("global_load_dwordx4 %0, %1, off sc0 sc1\n\ts_waitcnt vmcnt(0)"
                 : "=v"(d) : "v"(a) : "memory");
    return d;
}

// zero h0+h1 (512KB), zero flags, transpose x -> xT[784][256]
__global__ void init_all(const float* __restrict__ x, float* __restrict__ xT,
                         uint4* __restrict__ hz, unsigned* __restrict__ flg) {
    int t = blockIdx.x, tid = threadIdx.x;
    xT[t * BATCH + tid] = x[tid * TSTEPS + t];
    int i = t * 256 + tid;
    if (i < (512 << 10) / 16) hz[i] = make_uint4(0u, 0u, 0u, 0u);
    if (i < NGRP * 64) flg[i] = 0u;
}

__device__ __forceinline__ float sigmoid_f(float v) {
    return __fdividef(1.f, 1.f + __expf(-v));
}
__device__ __forceinline__ float tanh_f(float v) {
    float e = __expf(fminf(fmaxf(2.f * v, -30.f), 30.f));
    return __fdividef(e - 1.f, e + 1.f);
}

// Persistent LSTM: 256 blocks = 16 groups(16 batch rows) x 16 col-slices(32 cols).
// W slice (128 gate-rows x 512) in 128KB LDS; c in registers; h exchanged via
// LLC (sc0 sc1); per-group 16-flag barrier, 4-lane dwordx4 polling.
__global__ __launch_bounds__(512)
void lstm_persist(const float* __restrict__ xT,     // [784][256]
                  const float* __restrict__ W_hh,   // [2048][512] fp32
                  const float* __restrict__ w_in,   // [2048]
                  const float* __restrict__ b_ih,
                  const float* __restrict__ b_hh,
                  __bf16* __restrict__ h0,          // [256][512] bf16
                  __bf16* __restrict__ h1,
                  float* __restrict__ hf,           // [256][512] fp32
                  unsigned* __restrict__ flg)
{
    __shared__ __align__(16) __bf16 wlds[128 * HID];  // 128 KB, XOR-swizzled
    __shared__ __align__(16) __bf16 hlds[16 * HID];   // 16 KB, XOR-swizzled
    __shared__ float gl[4][16][33];                   // gate exchange
    __shared__ float xl[16];

    const int tid  = threadIdx.x;
    const int lane = tid & 63;
    const int w    = tid >> 6;           // wave 0..7
    const int s    = w & 3;              // gate (i,f,g,o)
    const int ch   = w >> 2;             // col half (16 cols each)
    const int bg   = blockIdx.x >> 4;    // group (16)
    const int cs   = blockIdx.x & 15;    // col slice (16)
    const int b0   = bg * 16;
    const int j0   = cs * 32;
    const int rlo  = lane & 15;
    const int khi  = (lane >> 4) * 8;    // elements

    unsigned* flags = flg + bg * 64;     // 256B-separated per-group flag line

    // ---- stage W slice (128 rows x 512) into LDS once (fp32->bf16, swizzled) ----
    {
        int r = tid >> 2;                // local row 0..127
        int q = tid & 3;
        int gs = r >> 5, jj = r & 31;
        const float* src = W_hh + (size_t)(gs * HID + j0 + jj) * HID + q * 128;
        char* wp = (char*)wlds;
        unsigned rowb = (unsigned)r * (HID * 2);
        unsigned sw   = SWS(r);
        #pragma unroll
        for (int cc = 0; cc < 128; cc += 8) {
            float4 va = *(const float4*)(src + cc);
            float4 vb = *(const float4*)(src + cc + 4);
            bf16x8 pk;
            pk[0]=(__bf16)va.x; pk[1]=(__bf16)va.y; pk[2]=(__bf16)va.z; pk[3]=(__bf16)va.w;
            pk[4]=(__bf16)vb.x; pk[5]=(__bf16)vb.y; pk[6]=(__bf16)vb.z; pk[7]=(__bf16)vb.w;
            *(bf16x8*)(wp + ((rowb + (unsigned)(q * 128 + cc) * 2) ^ sw)) = pk;
        }
    }

    // cell mapping (tid<256 active): row Rc=tid>>4 (0..15), cols c2,c2+1 (of 32)
    const int Rc = tid >> 4;
    const int c2 = (tid & 15) * 2;
    float win_r[4][2], bias_r[4][2];
    #pragma unroll
    for (int g = 0; g < 4; ++g)
        #pragma unroll
        for (int ii = 0; ii < 2; ++ii) {
            int idx = g * HID + j0 + c2 + ii;
            win_r[g][ii]  = w_in[idx];
            bias_r[g][ii] = b_ih[idx] + b_hh[idx];
        }
    float creg[2] = {0.f, 0.f};

    // staging mapping: row rS (0..15), segment seg (0..31) of 16 cols (32B)
    const int rS  = tid & 15;
    const int seg = tid >> 4;
    const unsigned rowbS = (unsigned)rS * (HID * 2);
    const unsigned swS   = SWS(rS);

    // B-fragment base: local W row rB = s*32 + ch*16 + rlo
    const unsigned rBb = (unsigned)(s * 32 + ch * 16 + rlo) * (HID * 2);
    const unsigned swB = SWS(rlo);
    const char* wbp = (const char*)wlds;
    const char* hbp = (const char*)hlds;
    char* hwp = (char*)hlds;

    __syncthreads();

    for (int t = 0; t < TSTEPS; ++t) {
        const __bf16* hprev = (t & 1) ? h1 : h0;
        __bf16* hnext       = (t & 1) ? h0 : h1;

        // ---- stage h slice (16 rows x 512) into LDS via LLC loads ----
        {
            const __bf16* gsrc = hprev + (size_t)(b0 + rS) * HID + seg * 16;
            i32x4 t0, t1;
            LDX4_CC(t0, gsrc);
            LDX4_CC(t1, gsrc + 8);
            asm volatile("s_waitcnt vmcnt(0)" ::: "memory");
            __builtin_amdgcn_sched_barrier(0);
            unsigned base = rowbS + (unsigned)seg * 32u;
            *(i32x4*)(hwp + ((base +  0u) ^ swS)) = t0;
            *(i32x4*)(hwp + ((base + 16u) ^ swS)) = t1;
        }
        if (tid < 16) xl[tid] = xT[t * BATCH + b0 + tid];
        __syncthreads();   // hlds + xl ready

        // ---- gates tile: 16 rows x 16 cols for gate s, col-half ch ----
        f32x4 acc0 = {0.f,0.f,0.f,0.f};
        #pragma unroll
        for (int ks = 0; ks < 16; ++ks) {
            unsigned colb = (unsigned)(khi * 2 + ks * 64);
            bf16x8 a0 = *(const bf16x8*)(hbp + (((unsigned)rlo * 1024u + colb) ^ SWS(rlo)));
            bf16x8 b  = *(const bf16x8*)(wbp + ((rBb + colb) ^ swB));
            acc0 = __builtin_amdgcn_mfma_f32_16x16x32_bf16(a0, b, acc0, 0, 0, 0);
        }
        #pragma unroll
        for (int rr = 0; rr < 4; ++rr) {
            int rowl = (lane >> 4) * 4 + rr;   // D: col=lane&15, row=(lane>>4)*4+reg
            gl[s][rowl][ch * 16 + rlo] = acc0[rr];
        }
        __syncthreads();   // gl ready

        // ---- cell update (tid<256: 2 cols each), h write-through to LLC ----
        if (tid < 256) {
            float xv = xl[Rc];
            float hn2[2];
            #pragma unroll
            for (int ii = 0; ii < 2; ++ii) {
                int ccx = c2 + ii;
                float gi = gl[0][Rc][ccx] + xv * win_r[0][ii] + bias_r[0][ii];
                float gf = gl[1][Rc][ccx] + xv * win_r[1][ii] + bias_r[1][ii];
                float gg = gl[2][Rc][ccx] + xv * win_r[2][ii] + bias_r[2][ii];
                float go = gl[3][Rc][ccx] + xv * win_r[3][ii] + bias_r[3][ii];
                float cn = sigmoid_f(gf) * creg[ii] + sigmoid_f(gi) * tanh_f(gg);
                creg[ii] = cn;
                hn2[ii]  = sigmoid_f(go) * tanh_f(cn);
            }
            union { __bf16 b[2]; int i; } u;
            u.b[0] = (__bf16)hn2[0]; u.b[1] = (__bf16)hn2[1];
            __bf16* dst = hnext + (size_t)(b0 + Rc) * HID + j0 + c2;
            STOREDW_CC(dst, u.i);
            if (t == TSTEPS - 1)
                *(f32x2*)(hf + (size_t)(b0 + Rc) * HID + j0 + c2) = (f32x2){hn2[0], hn2[1]};
        }

        if (t == TSTEPS - 1) break;

        // ---- per-group flag barrier (16 producers, 4-lane x4 poll, no RMW) ----
        asm volatile("s_waitcnt vmcnt(0)" ::: "memory");   // h stores at LLC
        __syncthreads();                                   // whole block flushed
        unsigned tgt = (unsigned)(t + 1);
        if (tid == 0) STOREDW_CC(flags + cs, (int)tgt);
        if (tid < 4) {
            const unsigned* fp = flags + tid * 4;
            int bad;
            do {
                __builtin_amdgcn_s_sleep(1);
                i32x4 f = ldflags_cc(fp);
                bad = ((unsigned)f[0] < tgt) | ((unsigned)f[1] < tgt) |
                      ((unsigned)f[2] < tgt) | ((unsigned)f[3] < tgt);
            } while (__any(bad));
        }
        __syncthreads();   // group advanced; safe to read hprev
    }
}

// out[b][j] = h_T[b] . W_lin[j] + b_lin[j]
__global__ void head(const float* __restrict__ hfp, const float* __restrict__ Wl,
                     const float* __restrict__ bl_, float* __restrict__ out)
{
    __shared__ float hr[HID];
    int b = blockIdx.x;
    for (int k = threadIdx.x; k < HID; k += blockDim.x) hr[k] = hfp[b * HID + k];
    __syncthreads();
    int j = threadIdx.x;
    if (j < NCLS) {
        float acc = bl_[j];
        for (int k = 0; k < HID; ++k) acc += hr[k] * Wl[j * HID + k];
        out[b * NCLS + j] = acc;
    }
}

extern "C" void kernel_launch(void* const* d_in, const int* in_sizes, int n_in,
                              void* d_out, int out_size, void* d_ws, size_t ws_size,
                              hipStream_t stream) {
    const float* inputs = (const float*)d_in[0];
    const float* W_ih   = (const float*)d_in[1];
    const float* W_hh   = (const float*)d_in[2];
    const float* b_ih   = (const float*)d_in[3];
    const float* b_hh   = (const float*)d_in[4];
    const float* W_lin  = (const float*)d_in[5];
    const float* b_lin  = (const float*)d_in[6];

    // ws: h0 256K | h1 256K | hf 512K | xT 784K | flags 4K
    const size_t OFS_H1  = 256u << 10;
    const size_t OFS_HF  = 512u << 10;
    const size_t OFS_XT  = 1024u << 10;
    const size_t OFS_FLG = OFS_XT + (size_t)TSTEPS * BATCH * 4;   // 128B-aligned
    const size_t NEEDED  = OFS_FLG + NGRP * 64 * 4;
    if (ws_size < NEEDED) return;

    char* ws = (char*)d_ws;
    __bf16* h0 = (__bf16*)ws;
    __bf16* h1 = (__bf16*)(ws + OFS_H1);
    float*  hf = (float*)(ws + OFS_HF);
    float*  xT = (float*)(ws + OFS_XT);
    unsigned* flg = (unsigned*)(ws + OFS_FLG);

    init_all<<<TSTEPS, BATCH, 0, stream>>>(inputs, xT, (uint4*)h0, flg);

    lstm_persist<<<NBLK, 512, 0, stream>>>(xT, W_hh, W_ih, b_ih, b_hh,
                                           h0, h1, hf, flg);

    head<<<BATCH, 64, 0, stream>>>(hf, W_lin, b_lin, (float*)d_out);
}